// Round 2
// baseline (10979.745 us; speedup 1.0000x reference)
//
#include <hip/hip_runtime.h>
#include <cstdint>
#include <cstddef>

#define D_MODEL 512
#define N_HEADS 8
#define HEAD_E  64
#define SEQ_L   2048
#define BATCH   2
#define KSEL    38            // int(5*log(2048)) = 38
#define NSEL    40            // candidates kept (margin 2)
#define M_ROWS  (BATCH*SEQ_L) // 4096

// ---------------------------------------------------------------------------
// f32 GEMM: C = A @ W.T + b. Tile 64x64, BK=32, 256 thr, 4x4 micro.
// ---------------------------------------------------------------------------
__global__ __launch_bounds__(256) void gemm_bias_kernel(
    const float* __restrict__ A, const float* __restrict__ W,
    const float* __restrict__ bias, float* __restrict__ C,
    int M, int N, int K)
{
  __shared__ float As[64][36];
  __shared__ float Ws[64][36];
  const int t  = threadIdx.x;
  const int tx = t & 15, ty = t >> 4;
  const int bm = blockIdx.y << 6, bn = blockIdx.x << 6;

  float acc[4][4] = {};

  for (int k0 = 0; k0 < K; k0 += 32) {
    __syncthreads();
#pragma unroll
    for (int i = 0; i < 2; ++i) {
      int f = t + (i << 8);
      int r = f >> 3, c = (f & 7) << 2;
      *(float4*)&As[r][c] = *(const float4*)&A[(size_t)(bm + r) * K + k0 + c];
      *(float4*)&Ws[r][c] = *(const float4*)&W[(size_t)(bn + r) * K + k0 + c];
    }
    __syncthreads();
#pragma unroll
    for (int kk = 0; kk < 32; kk += 4) {
      float4 av[4], wv[4];
#pragma unroll
      for (int i = 0; i < 4; ++i) av[i] = *(const float4*)&As[ty * 4 + i][kk];
#pragma unroll
      for (int j = 0; j < 4; ++j) wv[j] = *(const float4*)&Ws[tx + 16 * j][kk];
#pragma unroll
      for (int i = 0; i < 4; ++i)
#pragma unroll
        for (int j = 0; j < 4; ++j)
          acc[i][j] += av[i].x * wv[j].x + av[i].y * wv[j].y +
                       av[i].z * wv[j].z + av[i].w * wv[j].w;
    }
  }

#pragma unroll
  for (int i = 0; i < 4; ++i) {
    int row = bm + ty * 4 + i;
#pragma unroll
    for (int j = 0; j < 4; ++j) {
      int col = bn + tx + 16 * j;
      C[(size_t)row * N + col] = acc[i][j] + bias[col];
    }
  }
}

// ---------------------------------------------------------------------------
// f64-accumulate GEMM (f32 inputs, exact products): Cd = A @ W.T + b (f64).
// Optionally also writes an f32-rounded copy Cf.
// ---------------------------------------------------------------------------
__global__ __launch_bounds__(256) void gemm_bias_f64_kernel(
    const float* __restrict__ A, const float* __restrict__ W,
    const float* __restrict__ bias, double* __restrict__ Cd,
    float* __restrict__ Cf, int M, int N, int K)
{
  __shared__ float As[64][36];
  __shared__ float Ws[64][36];
  const int t  = threadIdx.x;
  const int tx = t & 15, ty = t >> 4;
  const int bm = blockIdx.y << 6, bn = blockIdx.x << 6;

  double acc[4][4] = {};

  for (int k0 = 0; k0 < K; k0 += 32) {
    __syncthreads();
#pragma unroll
    for (int i = 0; i < 2; ++i) {
      int f = t + (i << 8);
      int r = f >> 3, c = (f & 7) << 2;
      *(float4*)&As[r][c] = *(const float4*)&A[(size_t)(bm + r) * K + k0 + c];
      *(float4*)&Ws[r][c] = *(const float4*)&W[(size_t)(bn + r) * K + k0 + c];
    }
    __syncthreads();
#pragma unroll
    for (int kk = 0; kk < 32; kk += 4) {
      float4 av[4], wv[4];
#pragma unroll
      for (int i = 0; i < 4; ++i) av[i] = *(const float4*)&As[ty * 4 + i][kk];
#pragma unroll
      for (int j = 0; j < 4; ++j) wv[j] = *(const float4*)&Ws[tx + 16 * j][kk];
#pragma unroll
      for (int i = 0; i < 4; ++i)
#pragma unroll
        for (int j = 0; j < 4; ++j)
          acc[i][j] += (double)av[i].x * (double)wv[j].x
                     + (double)av[i].y * (double)wv[j].y
                     + (double)av[i].z * (double)wv[j].z
                     + (double)av[i].w * (double)wv[j].w;
    }
  }

#pragma unroll
  for (int i = 0; i < 4; ++i) {
    int row = bm + ty * 4 + i;
#pragma unroll
    for (int j = 0; j < 4; ++j) {
      int col = bn + tx + 16 * j;
      double v = acc[i][j] + (double)bias[col];
      Cd[(size_t)row * N + col] = v;
      if (Cf) Cf[(size_t)row * N + col] = (float)v;
    }
  }
}

// ---------------------------------------------------------------------------
// Fused ProbSparse attention. grid (L/8, B*H), block 256 (4 waves).
// f32 fast scores (register-held, 64/thread) -> iterative top-40 per
// half-wave -> if boundary gap > 1e-4 use f32 set/weights, else f64 rescore
// of the 40 candidates and exact f64 top-38.
// ---------------------------------------------------------------------------
#define GROUPMAX(G, GM, GS)                                     \
  {                                                             \
    GM = -3.0e38f; GS = (G) * 16;                               \
    _Pragma("unroll")                                           \
    for (int jj = 0; jj < 16; ++jj) {                           \
      const int j = (G) * 16 + jj;                              \
      float cv = ((alive >> j) & 1ull) ? v[j] : -3.0e38f;       \
      if (cv > GM) { GM = cv; GS = j; }                         \
    }                                                           \
  }

__global__ __launch_bounds__(256) void attn_kernel(
    const double* __restrict__ Qd, const float* __restrict__ Kf,
    const double* __restrict__ Kd, const float* __restrict__ Vm,
    float* __restrict__ AO)
{
  __shared__ float  Ks[64][68];
  __shared__ float  Qs[8][68];
  __shared__ double Qsd[8][64];
  __shared__ float  sel_e[8][NSEL];
  __shared__ int    sel_s[8][NSEL];
  __shared__ float  sel_inv[8];

  const int t    = threadIdx.x;
  const int lane = t & 63;
  const int bh   = blockIdx.y;
  const int b    = bh >> 3, h = bh & 7;
  const int q0   = blockIdx.x << 3;
  const size_t rowbase = (size_t)b * SEQ_L;
  const float* Kb = Kf + rowbase * D_MODEL + h * HEAD_E;
  const float* Vb = Vm + rowbase * D_MODEL + h * HEAD_E;

  // stage the 8 Q rows: f64 + f32 copies (256 thr, one double2 each)
  {
    int r = t >> 5, c2 = t & 31;
    double2 qv = *(const double2*)&Qd[(rowbase + q0 + r) * D_MODEL + h * HEAD_E + 2 * c2];
    Qsd[r][2 * c2]     = qv.x;
    Qsd[r][2 * c2 + 1] = qv.y;
    Qs[r][2 * c2]      = (float)qv.x;
    Qs[r][2 * c2 + 1]  = (float)qv.y;
  }

  const int q  = t >> 5;   // 0..7
  const int s0 = t & 31;   // key lane within half-wave
  float v[64];             // scores: v[j] is key s = j*32 + s0

  // ---- fast score phase: 32 K-tiles of 64 keys ----
#pragma unroll
  for (int ti = 0; ti < 32; ++ti) {
    const int kt = ti << 6;
    __syncthreads();
#pragma unroll
    for (int i = 0; i < 4; ++i) {
      int f = t + (i << 8);
      int r = f >> 4, c = (f & 15) << 2;
      *(float4*)&Ks[r][c] = *(const float4*)&Kb[(size_t)(kt + r) * D_MODEL + c];
    }
    __syncthreads();
    float acc0 = 0.f, acc1 = 0.f;
#pragma unroll
    for (int e = 0; e < 64; e += 4) {
      float4 qv = *(const float4*)&Qs[q][e];
      float4 k0 = *(const float4*)&Ks[s0][e];
      float4 k1 = *(const float4*)&Ks[s0 + 32][e];
      acc0 += qv.x * k0.x + qv.y * k0.y + qv.z * k0.z + qv.w * k0.w;
      acc1 += qv.x * k1.x + qv.y * k1.y + qv.z * k1.z + qv.w * k1.w;
    }
    v[2 * ti]     = acc0 * 0.125f;
    v[2 * ti + 1] = acc1 * 0.125f;
  }

  // ---- top-40 selection per half-wave ----
  uint64_t alive = ~0ull;
  float gm0, gm1, gm2, gm3; int gs0, gs1, gs2, gs3;
  GROUPMAX(0, gm0, gs0)
  GROUPMAX(1, gm1, gs1)
  GROUPMAX(2, gm2, gs2)
  GROUPMAX(3, gm3, gs3)

  float m = 0.f, v37 = 0.f, v38 = 0.f;
  float myv0 = 0.f, myv1 = 0.f;
  int   myidx0 = 0, myidx1 = 0;

  for (int it = 0; it < NSEL; ++it) {
    float lm = gm0; int lj = gs0;
    if (gm1 > lm) { lm = gm1; lj = gs1; }
    if (gm2 > lm) { lm = gm2; lj = gs2; }
    if (gm3 > lm) { lm = gm3; lj = gs3; }
    float bv = lm;
    int   bs = (lj << 5) | s0;
#pragma unroll
    for (int off = 1; off <= 16; off <<= 1) {
      float ov = __shfl_xor(bv, off);
      int   os = __shfl_xor(bs, off);
      if (ov > bv || (ov == bv && os < bs)) { bv = ov; bs = os; }
    }
    if (it == 0)  m   = bv;
    if (it == 37) v37 = bv;
    if (it == 38) v38 = bv;
    if (it == s0)      { myv0 = bv; myidx0 = bs; }
    if (it == s0 + 32) { myv1 = bv; myidx1 = bs; }
    if (s0 == 0) sel_s[q][it] = bs;
    if (s0 == (bs & 31)) {            // owner invalidates + rescans its group
      int wj = bs >> 5;
      alive &= ~(1ull << wj);
      int g = wj >> 4;
      switch (g) {
        case 0:  GROUPMAX(0, gm0, gs0) break;
        case 1:  GROUPMAX(1, gm1, gs1) break;
        case 2:  GROUPMAX(2, gm2, gs2) break;
        default: GROUPMAX(3, gm3, gs3) break;
      }
    }
  }

  // ---- weights: fast path if f32 boundary gap is provably decisive ----
  const int c1 = s0 + 32;
  float w0, w1;
  if (v37 - v38 < 1e-4f) {
    // rare: f64 rescore of all 40 candidates, exact f64 top-38
    const double* qrow = &Qsd[q][0];
    const double* kr0 = Kd + (rowbase + myidx0) * D_MODEL + h * HEAD_E;
    const double* kr1 = Kd + (rowbase + ((s0 < 8) ? myidx1 : myidx0)) * D_MODEL + h * HEAD_E;
    double d0 = 0.0, d1 = 0.0;
#pragma unroll 4
    for (int e = 0; e < 64; e += 2) {
      double qa = qrow[e], qb = qrow[e + 1];
      double2 k0 = *(const double2*)&kr0[e];
      double2 k1 = *(const double2*)&kr1[e];
      d0 += qa * k0.x + qb * k0.y;
      d1 += qa * k1.x + qb * k1.y;
    }
    d0 *= 0.125; d1 *= 0.125;
    if (s0 >= 8) d1 = -3.0e300;
    const int base = ((t >> 5) & 1) << 5;   // half-wave base lane within wave
    double mxd = -3.0e300; int rank0 = 0, rank1 = 0;
    for (int j = 0; j < NSEL; ++j) {
      double dj = (j < 32) ? __shfl(d0, base + j, 64)
                           : __shfl(d1, base + (j - 32), 64);
      if (dj > mxd) mxd = dj;
      rank0 += (dj > d0) || (dj == d0 && j < s0);
      rank1 += (dj > d1) || (dj == d1 && j < c1);
    }
    w0 = (rank0 < KSEL) ? __expf((float)(d0 - mxd)) : 0.f;
    w1 = (s0 < 8 && rank1 < KSEL) ? __expf((float)(d1 - mxd)) : 0.f;
  } else {
    // common: f32 top-38 set is the exact set; slots 38,39 dropped
    w0 = __expf(myv0 - m);
    w1 = (s0 < 6) ? __expf(myv1 - m) : 0.f;
  }

  float psum = w0 + w1;
#pragma unroll
  for (int off = 1; off <= 16; off <<= 1) psum += __shfl_xor(psum, off);

  sel_e[q][s0] = w0;
  if (s0 < 8) sel_e[q][c1] = w1;
  if (s0 == 0) sel_inv[q] = 1.0f / psum;

  __syncthreads();

  // ---- PV: wave w handles queries 2w, 2w+1; lane = head dim e ----
  const int w = t >> 6;
#pragma unroll
  for (int qq = 0; qq < 2; ++qq) {
    int qi = w * 2 + qq;
    float inv = sel_inv[qi];
    float acc = 0.f;
#pragma unroll
    for (int j = 0; j < NSEL; ++j) {
      float p = sel_e[qi][j];
      int   s = sel_s[qi][j];
      acc += p * Vb[(size_t)s * D_MODEL + lane];
    }
    AO[(rowbase + q0 + qi) * D_MODEL + h * HEAD_E + lane] = acc * inv;
  }
}

// ---------------------------------------------------------------------------
extern "C" void kernel_launch(void* const* d_in, const int* in_sizes, int n_in,
                              void* d_out, int out_size, void* d_ws, size_t ws_size,
                              hipStream_t stream) {
  const float* x  = (const float*)d_in[0];
  const float* Wq = (const float*)d_in[1];
  const float* bq = (const float*)d_in[2];
  const float* Wk = (const float*)d_in[3];
  const float* bk = (const float*)d_in[4];
  const float* Wv = (const float*)d_in[5];
  const float* bv = (const float*)d_in[6];
  const float* Wo = (const float*)d_in[7];
  const float* bo = (const float*)d_in[8];
  float* out = (float*)d_out;

  char* ws = (char*)d_ws;
  const size_t MAT = (size_t)M_ROWS * D_MODEL;  // 2M elements
  double* Qd = (double*)ws;                     // 16 MB
  double* Kd = (double*)(ws + MAT * 8);         // 16 MB
  float*  Kf = (float*)(ws + MAT * 16);         // 8 MB
  float*  Vf = (float*)(ws + MAT * 20);         // 8 MB
  float*  AO = (float*)(ws + MAT * 24);         // 8 MB

  dim3 ggrid(D_MODEL / 64, M_ROWS / 64);  // (8, 64)
  gemm_bias_f64_kernel<<<ggrid, 256, 0, stream>>>(x, Wq, bq, Qd, nullptr, M_ROWS, D_MODEL, D_MODEL);
  gemm_bias_f64_kernel<<<ggrid, 256, 0, stream>>>(x, Wk, bk, Kd, Kf, M_ROWS, D_MODEL, D_MODEL);
  gemm_bias_kernel<<<ggrid, 256, 0, stream>>>(x, Wv, bv, Vf, M_ROWS, D_MODEL, D_MODEL);

  attn_kernel<<<dim3(SEQ_L / 8, BATCH * N_HEADS), 256, 0, stream>>>(Qd, Kf, Kd, Vf, AO);

  gemm_bias_kernel<<<ggrid, 256, 0, stream>>>(AO, Wo, bo, out, M_ROWS, D_MODEL, D_MODEL);
}

// Round 3
// 1271.476 us; speedup vs baseline: 8.6354x; 8.6354x over previous
//
#include <hip/hip_runtime.h>
#include <cstdint>
#include <cstddef>

#define D_MODEL 512
#define N_HEADS 8
#define HEAD_E  64
#define SEQ_L   2048
#define BATCH   2
#define KSEL    38            // int(5*log(2048)) = 38
#define NSEL    40            // candidates kept (margin 2)
#define M_ROWS  (BATCH*SEQ_L) // 4096

// ---------------------------------------------------------------------------
// f32 GEMM: C = A @ W.T + b. Tile 64x64, BK=32, 256 thr, 4x4 micro.
// ---------------------------------------------------------------------------
__global__ __launch_bounds__(256) void gemm_bias_kernel(
    const float* __restrict__ A, const float* __restrict__ W,
    const float* __restrict__ bias, float* __restrict__ C,
    int M, int N, int K)
{
  __shared__ float As[64][36];
  __shared__ float Ws[64][36];
  const int t  = threadIdx.x;
  const int tx = t & 15, ty = t >> 4;
  const int bm = blockIdx.y << 6, bn = blockIdx.x << 6;

  float acc[4][4] = {};

  for (int k0 = 0; k0 < K; k0 += 32) {
    __syncthreads();
#pragma unroll
    for (int i = 0; i < 2; ++i) {
      int f = t + (i << 8);
      int r = f >> 3, c = (f & 7) << 2;
      *(float4*)&As[r][c] = *(const float4*)&A[(size_t)(bm + r) * K + k0 + c];
      *(float4*)&Ws[r][c] = *(const float4*)&W[(size_t)(bn + r) * K + k0 + c];
    }
    __syncthreads();
#pragma unroll
    for (int kk = 0; kk < 32; kk += 4) {
      float4 av[4], wv[4];
#pragma unroll
      for (int i = 0; i < 4; ++i) av[i] = *(const float4*)&As[ty * 4 + i][kk];
#pragma unroll
      for (int j = 0; j < 4; ++j) wv[j] = *(const float4*)&Ws[tx + 16 * j][kk];
#pragma unroll
      for (int i = 0; i < 4; ++i)
#pragma unroll
        for (int j = 0; j < 4; ++j)
          acc[i][j] += av[i].x * wv[j].x + av[i].y * wv[j].y +
                       av[i].z * wv[j].z + av[i].w * wv[j].w;
    }
  }

#pragma unroll
  for (int i = 0; i < 4; ++i) {
    int row = bm + ty * 4 + i;
#pragma unroll
    for (int j = 0; j < 4; ++j) {
      int col = bn + tx + 16 * j;
      C[(size_t)row * N + col] = acc[i][j] + bias[col];
    }
  }
}

// ---------------------------------------------------------------------------
// f64-accumulate GEMM (f32 inputs, exact products): Cd = A @ W.T + b (f64).
// Optionally also writes an f32-rounded copy Cf.
// ---------------------------------------------------------------------------
__global__ __launch_bounds__(256) void gemm_bias_f64_kernel(
    const float* __restrict__ A, const float* __restrict__ W,
    const float* __restrict__ bias, double* __restrict__ Cd,
    float* __restrict__ Cf, int M, int N, int K)
{
  __shared__ float As[64][36];
  __shared__ float Ws[64][36];
  const int t  = threadIdx.x;
  const int tx = t & 15, ty = t >> 4;
  const int bm = blockIdx.y << 6, bn = blockIdx.x << 6;

  double acc[4][4] = {};

  for (int k0 = 0; k0 < K; k0 += 32) {
    __syncthreads();
#pragma unroll
    for (int i = 0; i < 2; ++i) {
      int f = t + (i << 8);
      int r = f >> 3, c = (f & 7) << 2;
      *(float4*)&As[r][c] = *(const float4*)&A[(size_t)(bm + r) * K + k0 + c];
      *(float4*)&Ws[r][c] = *(const float4*)&W[(size_t)(bn + r) * K + k0 + c];
    }
    __syncthreads();
#pragma unroll
    for (int kk = 0; kk < 32; kk += 4) {
      float4 av[4], wv[4];
#pragma unroll
      for (int i = 0; i < 4; ++i) av[i] = *(const float4*)&As[ty * 4 + i][kk];
#pragma unroll
      for (int j = 0; j < 4; ++j) wv[j] = *(const float4*)&Ws[tx + 16 * j][kk];
#pragma unroll
      for (int i = 0; i < 4; ++i)
#pragma unroll
        for (int j = 0; j < 4; ++j)
          acc[i][j] += (double)av[i].x * (double)wv[j].x
                     + (double)av[i].y * (double)wv[j].y
                     + (double)av[i].z * (double)wv[j].z
                     + (double)av[i].w * (double)wv[j].w;
    }
  }

#pragma unroll
  for (int i = 0; i < 4; ++i) {
    int row = bm + ty * 4 + i;
#pragma unroll
    for (int j = 0; j < 4; ++j) {
      int col = bn + tx + 16 * j;
      double v = acc[i][j] + (double)bias[col];
      Cd[(size_t)row * N + col] = v;
      if (Cf) Cf[(size_t)row * N + col] = (float)v;
    }
  }
}

// ---------------------------------------------------------------------------
// Fused ProbSparse attention v2 — wave-per-query, scratch-free.
// grid (L/4, B*H), block 256 = 4 waves. Wave w owns query q0+w.
// Score phase: 32 K-tiles of 64 keys staged in XOR-swizzled LDS (shared by
// all 4 waves); lane l computes score for key kt+l, writes to LDS S[w][key].
// Selection: lane loads its 32 scores (keys j*64+l) into regs; iterative
// top-40 via full-wave butterfly argmax w/ 2-group cached tournament.
// Weights: f32 fast path if 37/38 boundary gap > 1e-4, else exact f64
// rescore of the 40 candidates. PV via shfl-broadcast of (w, idx).
// ---------------------------------------------------------------------------
#define GMAX(G, GM, GS)                                         \
  {                                                             \
    GM = -3.0e38f; GS = (G) * 16;                               \
    _Pragma("unroll")                                           \
    for (int jj = 0; jj < 16; ++jj) {                           \
      const int j = (G) * 16 + jj;                              \
      float cv = ((alive >> j) & 1u) ? v[j] : -3.0e38f;         \
      if (cv > GM) { GM = cv; GS = j; }                         \
    }                                                           \
  }

__global__ __launch_bounds__(256, 3) void attn_kernel(
    const double* __restrict__ Qd, const float* __restrict__ Kf,
    const double* __restrict__ Kd, const float* __restrict__ Vm,
    float* __restrict__ AO)
{
  __shared__ float  Ks[64 * 64];     // float4-XOR-swizzled K tile (16 KB)
  __shared__ float  S[4][SEQ_L / 1]; // hold scores? no: [4][2048] = 32 KB
  __shared__ float  Qs[4][64];
  __shared__ double Qsd[4][64];

  const int t  = threadIdx.x;
  const int w  = t >> 6;    // wave id = query within block
  const int l  = t & 63;    // lane
  const int bh = blockIdx.y;
  const int b  = bh >> 3, h = bh & 7;
  const int q0 = blockIdx.x << 2;
  const size_t rowbase = (size_t)b * SEQ_L;
  const float* Kb = Kf + rowbase * D_MODEL + h * HEAD_E;
  const float* Vb = Vm + rowbase * D_MODEL + h * HEAD_E;

  // stage this block's 4 Q rows (f64 + f32 cast); thread t -> (row w, dim l)
  {
    double qv = Qd[(rowbase + q0 + w) * D_MODEL + h * HEAD_E + l];
    Qsd[w][l] = qv;
    Qs[w][l]  = (float)qv;
  }

  // ---- score phase: 32 tiles of 64 keys; runtime loop, static LDS layout ----
  for (int ti = 0; ti < 32; ++ti) {
    const int kt = ti << 6;
    __syncthreads();
#pragma unroll
    for (int i = 0; i < 4; ++i) {
      int f = t + (i << 8);              // 1024 float4 slots = 64 rows x 16
      int r = f >> 4, c4 = f & 15;
      ((float4*)Ks)[(r << 4) | (c4 ^ (r & 15))] =
          *(const float4*)&Kb[(size_t)(kt + r) * D_MODEL + (c4 << 2)];
    }
    __syncthreads();
    float acc = 0.f;
#pragma unroll
    for (int e4 = 0; e4 < 16; ++e4) {
      float4 kv = ((const float4*)Ks)[(l << 4) | (e4 ^ (l & 15))];
      float4 qv = *(const float4*)&Qs[w][e4 << 2];   // wave-uniform broadcast
      acc += qv.x * kv.x + qv.y * kv.y + qv.z * kv.z + qv.w * kv.w;
    }
    S[w][kt + l] = acc * 0.125f;        // 1/sqrt(64)
  }

  // lane's 32 scores (keys j*64 + l); same-lane RAW, no barrier needed
  float v[32];
#pragma unroll
  for (int j = 0; j < 32; ++j) v[j] = S[w][(j << 6) + l];

  // ---- iterative top-40 per wave ----
  uint32_t alive = 0xffffffffu;
  float gm0, gm1; int gs0, gs1;
  GMAX(0, gm0, gs0)
  GMAX(1, gm1, gs1)

  float m = 0.f, v37 = 0.f, v38 = 0.f, myv = 0.f;
  int   myidx = 0;

  for (int it = 0; it < NSEL; ++it) {
    float bv = gm0; int bj = gs0;
    if (gm1 > bv) { bv = gm1; bj = gs1; }
    int bs = (bj << 6) | l;             // global key index
#pragma unroll
    for (int off = 1; off < 64; off <<= 1) {
      float ov = __shfl_xor(bv, off);
      int   os = __shfl_xor(bs, off);
      if (ov > bv || (ov == bv && os < bs)) { bv = ov; bs = os; }
    }
    if (it == 0)  m   = bv;
    if (it == 37) v37 = bv;
    if (it == 38) v38 = bv;
    if (it == l)  { myv = bv; myidx = bs; }   // lane `it` owns candidate `it`
    if (l == (bs & 63)) {               // owner lane invalidates + rescans
      int wj = bs >> 6;
      alive &= ~(1u << wj);
      if (wj < 16) { GMAX(0, gm0, gs0) }
      else         { GMAX(1, gm1, gs1) }
    }
  }

  // ---- weights: fast f32 path unless the 37/38 boundary is tight ----
  float myw;
  if (v37 - v38 < 1e-4f) {
    // rare: f64 rescore of all 40 candidates, exact f64 top-38
    double d = -1.0e300;
    if (l < NSEL) {
      const double* kr = Kd + (rowbase + myidx) * D_MODEL + h * HEAD_E;
      double acc = 0.0;
#pragma unroll 8
      for (int e = 0; e < 64; ++e) acc += Qsd[w][e] * kr[e];
      d = acc * 0.125;
    }
    double mxd = -1.0e300; int rank = 0;
    for (int j = 0; j < NSEL; ++j) {
      double dj = __shfl(d, j);
      int    ij = __shfl(myidx, j);
      if (dj > mxd) mxd = dj;
      rank += (dj > d) || (dj == d && ij < myidx);
    }
    myw = (l < NSEL && rank < KSEL) ? __expf((float)(d - mxd)) : 0.f;
  } else {
    // common: f32 top-38 set provably exact; slots 38,39 dropped
    myw = (l < KSEL) ? __expf(myv - m) : 0.f;
  }

  float psum = myw;
#pragma unroll
  for (int off = 1; off < 64; off <<= 1) psum += __shfl_xor(psum, off);
  const float inv = 1.0f / psum;

  // ---- PV: lane = head dim; broadcast (w, idx) from candidate lanes ----
  float acc = 0.f;
  for (int j = 0; j < NSEL; ++j) {
    float wj = __shfl(myw, j);
    int   sj = __shfl(myidx, j);
    if (wj != 0.f)                       // wave-uniform skip
      acc += wj * Vb[(size_t)sj * D_MODEL + l];
  }
  AO[(rowbase + q0 + w) * D_MODEL + h * HEAD_E + l] = acc * inv;
}

// ---------------------------------------------------------------------------
extern "C" void kernel_launch(void* const* d_in, const int* in_sizes, int n_in,
                              void* d_out, int out_size, void* d_ws, size_t ws_size,
                              hipStream_t stream) {
  const float* x  = (const float*)d_in[0];
  const float* Wq = (const float*)d_in[1];
  const float* bq = (const float*)d_in[2];
  const float* Wk = (const float*)d_in[3];
  const float* bk = (const float*)d_in[4];
  const float* Wv = (const float*)d_in[5];
  const float* bv = (const float*)d_in[6];
  const float* Wo = (const float*)d_in[7];
  const float* bo = (const float*)d_in[8];
  float* out = (float*)d_out;

  char* ws = (char*)d_ws;
  const size_t MAT = (size_t)M_ROWS * D_MODEL;  // 2M elements
  double* Qd = (double*)ws;                     // 16 MB
  double* Kd = (double*)(ws + MAT * 8);         // 16 MB
  float*  Kf = (float*)(ws + MAT * 16);         // 8 MB
  float*  Vf = (float*)(ws + MAT * 20);         // 8 MB
  float*  AO = (float*)(ws + MAT * 24);         // 8 MB

  dim3 ggrid(D_MODEL / 64, M_ROWS / 64);  // (8, 64)
  gemm_bias_f64_kernel<<<ggrid, 256, 0, stream>>>(x, Wq, bq, Qd, nullptr, M_ROWS, D_MODEL, D_MODEL);
  gemm_bias_f64_kernel<<<ggrid, 256, 0, stream>>>(x, Wk, bk, Kd, Kf, M_ROWS, D_MODEL, D_MODEL);
  gemm_bias_kernel<<<ggrid, 256, 0, stream>>>(x, Wv, bv, Vf, M_ROWS, D_MODEL, D_MODEL);

  attn_kernel<<<dim3(SEQ_L / 4, BATCH * N_HEADS), 256, 0, stream>>>(Qd, Kf, Kd, Vf, AO);

  gemm_bias_kernel<<<ggrid, 256, 0, stream>>>(AO, Wo, bo, out, M_ROWS, D_MODEL, D_MODEL);
}

// Round 4
// 1071.109 us; speedup vs baseline: 10.2508x; 1.1871x over previous
//
#include <hip/hip_runtime.h>
#include <cstdint>
#include <cstddef>

#define D_MODEL 512
#define N_HEADS 8
#define HEAD_E  64
#define SEQ_L   2048
#define BATCH   2
#define KSEL    38            // int(5*log(2048)) = 38
#define M_ROWS  (BATCH*SEQ_L) // 4096

// ---------------------------------------------------------------------------
// f32 GEMM: C = A @ W.T + b. Tile 64x64, BK=32, 256 thr, 4x4 micro.
// ---------------------------------------------------------------------------
__global__ __launch_bounds__(256) void gemm_bias_kernel(
    const float* __restrict__ A, const float* __restrict__ W,
    const float* __restrict__ bias, float* __restrict__ C,
    int M, int N, int K)
{
  __shared__ float As[64][36];
  __shared__ float Ws[64][36];
  const int t  = threadIdx.x;
  const int tx = t & 15, ty = t >> 4;
  const int bm = blockIdx.y << 6, bn = blockIdx.x << 6;

  float acc[4][4] = {};

  for (int k0 = 0; k0 < K; k0 += 32) {
    __syncthreads();
#pragma unroll
    for (int i = 0; i < 2; ++i) {
      int f = t + (i << 8);
      int r = f >> 3, c = (f & 7) << 2;
      *(float4*)&As[r][c] = *(const float4*)&A[(size_t)(bm + r) * K + k0 + c];
      *(float4*)&Ws[r][c] = *(const float4*)&W[(size_t)(bn + r) * K + k0 + c];
    }
    __syncthreads();
#pragma unroll
    for (int kk = 0; kk < 32; kk += 4) {
      float4 av[4], wv[4];
#pragma unroll
      for (int i = 0; i < 4; ++i) av[i] = *(const float4*)&As[ty * 4 + i][kk];
#pragma unroll
      for (int j = 0; j < 4; ++j) wv[j] = *(const float4*)&Ws[tx + 16 * j][kk];
#pragma unroll
      for (int i = 0; i < 4; ++i)
#pragma unroll
        for (int j = 0; j < 4; ++j)
          acc[i][j] += av[i].x * wv[j].x + av[i].y * wv[j].y +
                       av[i].z * wv[j].z + av[i].w * wv[j].w;
    }
  }

#pragma unroll
  for (int i = 0; i < 4; ++i) {
    int row = bm + ty * 4 + i;
#pragma unroll
    for (int j = 0; j < 4; ++j) {
      int col = bn + tx + 16 * j;
      C[(size_t)row * N + col] = acc[i][j] + bias[col];
    }
  }
}

// ---------------------------------------------------------------------------
// f64-accumulate GEMM (f32 inputs, exact products): Cd = A @ W.T + b (f64).
// Optionally also writes an f32-rounded copy Cf.
// ---------------------------------------------------------------------------
__global__ __launch_bounds__(256) void gemm_bias_f64_kernel(
    const float* __restrict__ A, const float* __restrict__ W,
    const float* __restrict__ bias, double* __restrict__ Cd,
    float* __restrict__ Cf, int M, int N, int K)
{
  __shared__ float As[64][36];
  __shared__ float Ws[64][36];
  const int t  = threadIdx.x;
  const int tx = t & 15, ty = t >> 4;
  const int bm = blockIdx.y << 6, bn = blockIdx.x << 6;

  double acc[4][4] = {};

  for (int k0 = 0; k0 < K; k0 += 32) {
    __syncthreads();
#pragma unroll
    for (int i = 0; i < 2; ++i) {
      int f = t + (i << 8);
      int r = f >> 3, c = (f & 7) << 2;
      *(float4*)&As[r][c] = *(const float4*)&A[(size_t)(bm + r) * K + k0 + c];
      *(float4*)&Ws[r][c] = *(const float4*)&W[(size_t)(bn + r) * K + k0 + c];
    }
    __syncthreads();
#pragma unroll
    for (int kk = 0; kk < 32; kk += 4) {
      float4 av[4], wv[4];
#pragma unroll
      for (int i = 0; i < 4; ++i) av[i] = *(const float4*)&As[ty * 4 + i][kk];
#pragma unroll
      for (int j = 0; j < 4; ++j) wv[j] = *(const float4*)&Ws[tx + 16 * j][kk];
#pragma unroll
      for (int i = 0; i < 4; ++i)
#pragma unroll
        for (int j = 0; j < 4; ++j)
          acc[i][j] += (double)av[i].x * (double)wv[j].x
                     + (double)av[i].y * (double)wv[j].y
                     + (double)av[i].z * (double)wv[j].z
                     + (double)av[i].w * (double)wv[j].w;
    }
  }

#pragma unroll
  for (int i = 0; i < 4; ++i) {
    int row = bm + ty * 4 + i;
#pragma unroll
    for (int j = 0; j < 4; ++j) {
      int col = bn + tx + 16 * j;
      double v = acc[i][j] + (double)bias[col];
      Cd[(size_t)row * N + col] = v;
      if (Cf) Cf[(size_t)row * N + col] = (float)v;
    }
  }
}

// ---------------------------------------------------------------------------
// Fused ProbSparse attention v3 — wave-per-query, register scores,
// threshold+compact+bitonic selection.
// grid (L/4, B*H), block 256 = 4 waves. Wave w owns query q0+w.
// Score phase: 32 K-tiles (64 keys) in XOR-swizzled LDS; Q hoisted to
// 16 float4 registers; scores accumulate straight into v[32] (full unroll).
// Selection: wave max -> bisect threshold T with 40<=count(>=T)<=64 ->
// ballot-compact (index order) into LDS -> 64-wide bitonic sort
// (value desc, index asc) -> rank == lane. Fast f32 softmax if the
// rank37/rank38 gap > 1e-4, else exact f64 rescore of all candidates.
// ---------------------------------------------------------------------------
__global__ __launch_bounds__(256) void attn_kernel(
    const double* __restrict__ Qd, const float* __restrict__ Kf,
    const double* __restrict__ Kd, const float* __restrict__ Vm,
    float* __restrict__ AO)
{
  __shared__ float  Ks[64 * 64];     // swizzled float4 K tile, 16 KB
  __shared__ double Qsd[4][64];      // f64 Q rows for rescore, 2 KB
  __shared__ float  cvs[4][64];      // compacted candidate values
  __shared__ int    cis[4][64];      // compacted candidate indices

  const int t  = threadIdx.x;
  const int w  = t >> 6;    // wave id = query within block
  const int l  = t & 63;    // lane
  const int bh = blockIdx.y;
  const int b  = bh >> 3, h = bh & 7;
  const int q0 = blockIdx.x << 2;
  const size_t rowbase = (size_t)b * SEQ_L;
  const float* Kb = Kf + rowbase * D_MODEL + h * HEAD_E;
  const float* Vb = Vm + rowbase * D_MODEL + h * HEAD_E;

  // stage f64 Q rows; thread t -> (row w, dim l)
  Qsd[w][l] = Qd[(rowbase + q0 + w) * D_MODEL + h * HEAD_E + l];
  __syncthreads();

  // hoist Q (f32) into registers: 16 float4
  float4 q_r[16];
#pragma unroll
  for (int e4 = 0; e4 < 16; ++e4) {
    double2 d0 = *(const double2*)&Qsd[w][e4 * 4];
    double2 d1 = *(const double2*)&Qsd[w][e4 * 4 + 2];
    q_r[e4] = make_float4((float)d0.x, (float)d0.y, (float)d1.x, (float)d1.y);
  }

  // ---- score phase: 32 tiles of 64 keys, scores straight to registers ----
  float v[32];               // v[ti] = score of key ti*64 + l
#pragma unroll
  for (int ti = 0; ti < 32; ++ti) {
    __syncthreads();
#pragma unroll
    for (int i = 0; i < 4; ++i) {
      int f = t + (i << 8);              // 1024 float4 slots = 64 rows x 16
      int r = f >> 4, c4 = f & 15;
      ((float4*)Ks)[(r << 4) | (c4 ^ (r & 15))] =
          *(const float4*)&Kb[(size_t)((ti << 6) + r) * D_MODEL + (c4 << 2)];
    }
    __syncthreads();
    float a0 = 0.f, a1 = 0.f, a2 = 0.f, a3 = 0.f;
#pragma unroll
    for (int e4 = 0; e4 < 16; e4 += 4) {
      float4 k0 = ((const float4*)Ks)[(l << 4) | ((e4 + 0) ^ (l & 15))];
      float4 k1 = ((const float4*)Ks)[(l << 4) | ((e4 + 1) ^ (l & 15))];
      float4 k2 = ((const float4*)Ks)[(l << 4) | ((e4 + 2) ^ (l & 15))];
      float4 k3 = ((const float4*)Ks)[(l << 4) | ((e4 + 3) ^ (l & 15))];
      a0 += q_r[e4+0].x*k0.x + q_r[e4+0].y*k0.y + q_r[e4+0].z*k0.z + q_r[e4+0].w*k0.w;
      a1 += q_r[e4+1].x*k1.x + q_r[e4+1].y*k1.y + q_r[e4+1].z*k1.z + q_r[e4+1].w*k1.w;
      a2 += q_r[e4+2].x*k2.x + q_r[e4+2].y*k2.y + q_r[e4+2].z*k2.z + q_r[e4+2].w*k2.w;
      a3 += q_r[e4+3].x*k3.x + q_r[e4+3].y*k3.y + q_r[e4+3].z*k3.z + q_r[e4+3].w*k3.w;
    }
    v[ti] = ((a0 + a1) + (a2 + a3)) * 0.125f;   // 1/sqrt(64)
  }

  // ---- selection: wave max ----
  float m = v[0];
#pragma unroll
  for (int j = 1; j < 32; ++j) m = fmaxf(m, v[j]);
#pragma unroll
  for (int off = 1; off < 64; off <<= 1) m = fmaxf(m, __shfl_xor(m, off));

  auto countge = [&](float T) -> int {
    int c = 0;
#pragma unroll
    for (int j = 0; j < 32; ++j) c += (v[j] >= T) ? 1 : 0;
#pragma unroll
    for (int off = 1; off < 64; off <<= 1) c += __shfl_xor(c, off);
    return c;  // wave-uniform
  };

  // bisect threshold: invariant count(>=lo) >= 40; shrink until <= 64
  float lo = m - 0.5f;
  int C = countge(lo);
  float step = 1.0f;
  while (C < 40) {                    // widen (scores bounded, ~2 iters max)
    lo -= step; step *= 2.0f;
    if (step > 1.0e30f) { lo = -3.0e38f; C = 2048; break; }
    C = countge(lo);
  }
  float hi = m;
  for (int it = 0; it < 24 && C > 64; ++it) {
    float mid = 0.5f * (lo + hi);
    int cm = countge(mid);
    if (cm >= 40) { lo = mid; C = cm; } else hi = mid;
  }
  const int C2 = (C < 64) ? C : 64;

  // ---- ballot-compact candidates (>= lo) in index order ----
  int base = 0;
#pragma unroll
  for (int j = 0; j < 32; ++j) {
    bool in = (v[j] >= lo);
    unsigned long long mk = __ballot(in);
    if (in) {
      int pos = base + (int)__popcll(mk & ((1ull << l) - 1ull));
      if (pos < 64) { cvs[w][pos] = v[j]; cis[w][pos] = (j << 6) | l; }
    }
    base += (int)__popcll(mk);
  }
  __syncthreads();   // cheap safety for intra-wave LDS RAW across lanes

  float cval = (l < C2) ? cvs[w][l] : -3.0e38f;
  int   cidx = (l < C2) ? cis[w][l] : (SEQ_L + l);

  // ---- bitonic sort 64 lanes: value desc, index asc on ties ----
#pragma unroll
  for (int sz = 2; sz <= 64; sz <<= 1) {
#pragma unroll
    for (int st = sz >> 1; st >= 1; st >>= 1) {
      float ov = __shfl_xor(cval, st);
      int   oi = __shfl_xor(cidx, st);
      bool ob    = (ov > cval) || ((ov == cval) && (oi < cidx));
      bool dir   = ((l & sz) == 0);
      bool lower = ((l & st) == 0);
      bool take  = (ob == (lower == dir));
      if (take) { cval = ov; cidx = oi; }
    }
  }

  // ---- weights ----
  float v37 = __shfl(cval, 37);
  float v38 = __shfl(cval, 38);
  const bool tight = (v37 - v38 < 1e-4f) || (C > 64);
  float myw;
  if (!tight) {
    // f32 top-38 set provably exact; lane = rank
    myw = (l < KSEL) ? __expf(cval - m) : 0.f;
  } else {
    // rare: f64 rescore of all candidates, exact f64 top-38
    double d = -1.0e300;
    if (l < C2) {
      const double* kr = Kd + (rowbase + cidx) * D_MODEL + h * HEAD_E;
      double acc = 0.0;
#pragma unroll 8
      for (int e = 0; e < 64; ++e) acc += Qsd[w][e] * kr[e];
      d = acc * 0.125;
    }
    int myi = (l < C2) ? cidx : (SEQ_L + l);
    double mxd = -1.0e300; int rank = 0;
    for (int j = 0; j < 64; ++j) {
      double dj = __shfl(d, j);
      int    ij = __shfl(myi, j);
      if (dj > mxd) mxd = dj;
      rank += (dj > d) || ((dj == d) && (ij < myi));
    }
    myw = (l < C2 && rank < KSEL) ? __expf((float)(d - mxd)) : 0.f;
  }

  float psum = myw;
#pragma unroll
  for (int off = 1; off < 64; off <<= 1) psum += __shfl_xor(psum, off);
  const float inv = 1.0f / psum;

  // ---- PV: lane = head dim; broadcast (weight, idx) from candidate lanes ----
  float acc = 0.f;
  const int nn = tight ? 64 : KSEL;
  for (int j = 0; j < nn; ++j) {
    float wj = __shfl(myw, j);        // wave-uniform
    if (wj != 0.f) {
      int sj = __shfl(cidx, j);
      acc += wj * Vb[(size_t)sj * D_MODEL + l];
    }
  }
  AO[(rowbase + q0 + w) * D_MODEL + h * HEAD_E + l] = acc * inv;
}

// ---------------------------------------------------------------------------
extern "C" void kernel_launch(void* const* d_in, const int* in_sizes, int n_in,
                              void* d_out, int out_size, void* d_ws, size_t ws_size,
                              hipStream_t stream) {
  const float* x  = (const float*)d_in[0];
  const float* Wq = (const float*)d_in[1];
  const float* bq = (const float*)d_in[2];
  const float* Wk = (const float*)d_in[3];
  const float* bk = (const float*)d_in[4];
  const float* Wv = (const float*)d_in[5];
  const float* bv = (const float*)d_in[6];
  const float* Wo = (const float*)d_in[7];
  const float* bo = (const float*)d_in[8];
  float* out = (float*)d_out;

  char* ws = (char*)d_ws;
  const size_t MAT = (size_t)M_ROWS * D_MODEL;  // 2M elements
  double* Qd = (double*)ws;                     // 16 MB
  double* Kd = (double*)(ws + MAT * 8);         // 16 MB
  float*  Kf = (float*)(ws + MAT * 16);         // 8 MB
  float*  Vf = (float*)(ws + MAT * 20);         // 8 MB
  float*  AO = (float*)(ws + MAT * 24);         // 8 MB

  dim3 ggrid(D_MODEL / 64, M_ROWS / 64);  // (8, 64)
  gemm_bias_f64_kernel<<<ggrid, 256, 0, stream>>>(x, Wq, bq, Qd, nullptr, M_ROWS, D_MODEL, D_MODEL);
  gemm_bias_f64_kernel<<<ggrid, 256, 0, stream>>>(x, Wk, bk, Kd, Kf, M_ROWS, D_MODEL, D_MODEL);
  gemm_bias_kernel<<<ggrid, 256, 0, stream>>>(x, Wv, bv, Vf, M_ROWS, D_MODEL, D_MODEL);

  attn_kernel<<<dim3(SEQ_L / 4, BATCH * N_HEADS), 256, 0, stream>>>(Qd, Kf, Kd, Vf, AO);

  gemm_bias_kernel<<<ggrid, 256, 0, stream>>>(AO, Wo, bo, out, M_ROWS, D_MODEL, D_MODEL);
}